// Round 4
// baseline (790.327 us; speedup 1.0000x reference)
//
#include <hip/hip_runtime.h>

// 2-layer GRU (B=1024, T=512, F=128, H=64) + ReLU + FC(64->18), fp32 in/out.
//
// R4: two kernels.
//  A) state_to_f16: full-chip f32->f16 convert of `state` into d_ws (~65us).
//  B) gru_fused2: 64 blocks x 512 thr (8 waves). Waves 0-3 = L0 (full cell:
//     12 x-MFMAs from register f16 x-ring + 6 h-MFMAs), waves 4-7 = L1
//     (lagged one step). ONE custom barrier per tick:
//         s_waitcnt lgkmcnt(0); s_barrier
//     (LDS-only drain -- global x prefetch stays IN FLIGHT across barriers;
//     x lands in private VGPRs so this is race-free; h-exchange needs only
//     LDS visibility). T-loop unrolled x4 so the 4-slot x ring is static.
//     x loads: 8 x b128 every other tick, issue-to-use distance = 2 ticks.

#define Tn 512
#define Fn 128
#define Hn 64
#define An 18
#define HS 72   // h row stride in halves: 144B rows -> only 2-way LDS aliasing (free)

typedef _Float16 half8 __attribute__((ext_vector_type(8)));
typedef _Float16 half4 __attribute__((ext_vector_type(4)));
typedef float f32x4 __attribute__((ext_vector_type(4)));

#define MFMA(a, b, c) __builtin_amdgcn_mfma_f32_16x16x32_f16((a), (b), (c), 0, 0, 0)
// LDS-only barrier: do NOT drain vmcnt (x prefetch crosses barriers in VGPRs).
#define BAR() asm volatile("s_waitcnt lgkmcnt(0)\n\ts_barrier" ::: "memory")

// Clamp-free: exp2(+-inf) saturates, rcp(inf)->0.
static __device__ __forceinline__ float sigm(float x) {
    return __builtin_amdgcn_rcpf(1.0f + __builtin_amdgcn_exp2f(-1.4426950408889634f * x));
}
static __device__ __forceinline__ float tanh_f(float x) {
    return 2.0f * __builtin_amdgcn_rcpf(1.0f + __builtin_amdgcn_exp2f(-2.8853900817779268f * x)) - 1.0f;
}

__global__ __launch_bounds__(256) void state_to_f16(const float* __restrict__ in,
                                                    _Float16* __restrict__ out, int n4) {
    int i = blockIdx.x * blockDim.x + threadIdx.x;
    const int stride = gridDim.x * blockDim.x;
    for (; i < n4; i += stride) {
        f32x4 v = ((const f32x4*)in)[i];
        half4 h;
#pragma unroll
        for (int j = 0; j < 4; ++j) h[j] = (_Float16)v[j];
        ((half4*)out)[i] = h;
    }
}

template <bool XF16>
__global__ __launch_bounds__(512) void gru_fused2(
    const float* __restrict__ state, const _Float16* __restrict__ statef16,
    const float* __restrict__ Wih0, const float* __restrict__ Whh0,
    const float* __restrict__ bih0, const float* __restrict__ bhh0,
    const float* __restrict__ Wih1, const float* __restrict__ Whh1,
    const float* __restrict__ bih1, const float* __restrict__ bhh1,
    const float* __restrict__ fcw, const float* __restrict__ fcb,
    float* __restrict__ out)
{
    const int tid  = threadIdx.x;
    const int wv8  = tid >> 6;
    const int lane = tid & 63, c = lane & 15, q = lane >> 4;
    const bool isL0 = (wv8 < 4);
    const int wv   = wv8 & 3;
    const int r0   = blockIdx.x * 16;
    const int gc   = wv * 16 + c;

    __shared__ __align__(16) _Float16 h0buf[2][16 * HS];
    __shared__ __align__(16) _Float16 h1buf[2][16 * HS];
    __shared__ float fbuf[16 * 64];

    for (int i = tid; i < 2 * 16 * HS; i += 512) {
        (&h0buf[0][0])[i] = (_Float16)0.0f;
        (&h1buf[0][0])[i] = (_Float16)0.0f;
    }

    // L0: W[0..11] = Wih0 B-frags (gsel*4+ks), W[12..17] = Whh0 (12+gsel*2+ks)
    // L1: W[0..5]  = Wih1 (gsel*2+ks),         W[6..11]  = Whh1 (6+gsel*2+ks)
    half8 W[18];
    f32x4 bias0, bias1, bias2, bias3;
    f32x4 hreg = {0.f, 0.f, 0.f, 0.f};
    half8 xr[4][4];     // L0 + XF16: 4-slot x ring (f16 A-frags)
    f32x4 xp[8];        // L0 fallback: f32 x buffer

    const _Float16* sx = statef16 + (size_t)(r0 + c) * (Tn * Fn) + q * 8;
    const float* srow = state + (size_t)(r0 + c) * (Tn * Fn);

    if (isL0) {
#pragma unroll
        for (int gsel = 0; gsel < 3; ++gsel) {
            const int g = gsel * 64 + gc;
#pragma unroll
            for (int ks = 0; ks < 4; ++ks) {
                const float* p = Wih0 + g * Fn + ks * 32 + q * 8;
#pragma unroll
                for (int j = 0; j < 8; ++j) W[gsel * 4 + ks][j] = (_Float16)p[j];
            }
#pragma unroll
            for (int ks = 0; ks < 2; ++ks) {
                const float* p = Whh0 + g * Hn + ks * 32 + q * 8;
#pragma unroll
                for (int j = 0; j < 8; ++j) W[12 + gsel * 2 + ks][j] = (_Float16)p[j];
            }
        }
        const float br = bih0[gc] + bhh0[gc];
        const float bz = bih0[64 + gc] + bhh0[64 + gc];
        const float bxn = bih0[128 + gc];
        const float bhn = bhh0[128 + gc];
        bias0 = (f32x4){br, br, br, br};
        bias1 = (f32x4){bz, bz, bz, bz};
        bias2 = (f32x4){bxn, bxn, bxn, bxn};
        bias3 = (f32x4){bhn, bhn, bhn, bhn};
        if (XF16) {
            // preload slots 0,1 = x(0),x(1); slots 2,3 filled at tb=0,k=0
#pragma unroll
            for (int s = 0; s < 2; ++s)
#pragma unroll
                for (int ks = 0; ks < 4; ++ks)
                    xr[s][ks] = *(const half8*)(sx + (size_t)s * Fn + ks * 32);
        } else {
#pragma unroll
            for (int ks = 0; ks < 4; ++ks) {
                xp[2 * ks]     = *(const f32x4*)(srow + ks * 32 + q * 8);
                xp[2 * ks + 1] = *(const f32x4*)(srow + ks * 32 + q * 8 + 4);
            }
        }
    } else {
#pragma unroll
        for (int gsel = 0; gsel < 3; ++gsel) {
            const int g = gsel * 64 + gc;
#pragma unroll
            for (int ks = 0; ks < 2; ++ks) {
                const float* pa = Wih1 + g * Hn + ks * 32 + q * 8;
                const float* pb = Whh1 + g * Hn + ks * 32 + q * 8;
#pragma unroll
                for (int j = 0; j < 8; ++j) {
                    W[gsel * 2 + ks][j]     = (_Float16)pa[j];
                    W[6 + gsel * 2 + ks][j] = (_Float16)pb[j];
                }
            }
        }
        const float br = bih1[gc] + bhh1[gc];
        const float bz = bih1[64 + gc] + bhh1[64 + gc];
        const float bxn = bih1[128 + gc];
        const float bhn = bhh1[128 + gc];
        bias0 = (f32x4){br, br, br, br};
        bias1 = (f32x4){bz, bz, bz, bz};
        bias2 = (f32x4){bxn, bxn, bxn, bxn};
        bias3 = (f32x4){bhn, bhn, bhn, bhn};
    }

    const int ardr = c * HS + q * 8;      // A-frag read base (+32 for ks=1)
    const int wrow = (q * 4) * HS + gc;   // C-layout write base (+i*HS)

    __syncthreads();   // h-init + weight staging visible

    // Ticks 0..Tn-1 (unrolled x4); tick t: L0 -> h0(t), L1 -> h1(t-1) (t>=1).
    for (int tb = 0; tb < Tn; tb += 4) {
#pragma unroll
        for (int k = 0; k < 4; ++k) {
            const int t = tb + k;
            const int pr = (t & 1) ^ 1, pw = t & 1;
            if (isL0) {
                // h-frag reads first (latency overlaps x-MFMAs)
                const half8 hf0 = *(const half8*)&h0buf[pr][ardr];
                const half8 hf1 = *(const half8*)&h0buf[pr][ardr + 32];
                half8 xf[4];
                if (XF16) {
                    if ((k & 1) == 0) {   // issue 2 steps of x, distance-2
                        const int ta = (t + 2 < Tn) ? t + 2 : Tn - 1;
                        const int tb2 = (t + 3 < Tn) ? t + 3 : Tn - 1;
#pragma unroll
                        for (int ks = 0; ks < 4; ++ks)
                            xr[(k + 2) & 3][ks] = *(const half8*)(sx + (size_t)ta * Fn + ks * 32);
#pragma unroll
                        for (int ks = 0; ks < 4; ++ks)
                            xr[(k + 3) & 3][ks] = *(const half8*)(sx + (size_t)tb2 * Fn + ks * 32);
                    }
#pragma unroll
                    for (int ks = 0; ks < 4; ++ks) xf[ks] = xr[k][ks];
                } else {
#pragma unroll
                    for (int ks = 0; ks < 4; ++ks)
#pragma unroll
                        for (int i = 0; i < 4; ++i) {
                            xf[ks][i]     = (_Float16)xp[2 * ks][i];
                            xf[ks][4 + i] = (_Float16)xp[2 * ks + 1][i];
                        }
                    const int tnx = (t + 1 < Tn) ? t + 1 : t;
#pragma unroll
                    for (int ks = 0; ks < 4; ++ks) {
                        xp[2 * ks]     = *(const f32x4*)(srow + (size_t)tnx * Fn + ks * 32 + q * 8);
                        xp[2 * ks + 1] = *(const f32x4*)(srow + (size_t)tnx * Fn + ks * 32 + q * 8 + 4);
                    }
                }
                f32x4 accr = bias0, accz = bias1, accxn = bias2;
#pragma unroll
                for (int ks = 0; ks < 4; ++ks) {
                    accr  = MFMA(xf[ks], W[ks], accr);
                    accz  = MFMA(xf[ks], W[4 + ks], accz);
                    accxn = MFMA(xf[ks], W[8 + ks], accxn);
                }
                accr = MFMA(hf0, W[12], accr);
                accr = MFMA(hf1, W[13], accr);
                accz = MFMA(hf0, W[14], accz);
                accz = MFMA(hf1, W[15], accz);
                f32x4 acchn = MFMA(hf0, W[16], bias3);
                acchn = MFMA(hf1, W[17], acchn);
#pragma unroll
                for (int i = 0; i < 4; ++i) {
                    const float rg = sigm(accr[i]);
                    const float zg = sigm(accz[i]);
                    const float ng = tanh_f(accxn[i] + rg * acchn[i]);
                    hreg[i] = ng + zg * (hreg[i] - ng);
                }
#pragma unroll
                for (int i = 0; i < 4; ++i) h0buf[pw][wrow + i * HS] = (_Float16)hreg[i];
            } else {
                if (t >= 1) {
                    const half8 xf0 = *(const half8*)&h0buf[pr][ardr];
                    const half8 xf1 = *(const half8*)&h0buf[pr][ardr + 32];
                    const half8 hf0 = *(const half8*)&h1buf[pw][ardr];
                    const half8 hf1 = *(const half8*)&h1buf[pw][ardr + 32];
                    f32x4 accr = MFMA(xf0, W[0], bias0);
                    accr = MFMA(xf1, W[1], accr);
                    f32x4 accz = MFMA(xf0, W[2], bias1);
                    accz = MFMA(xf1, W[3], accz);
                    f32x4 accxn = MFMA(xf0, W[4], bias2);
                    accxn = MFMA(xf1, W[5], accxn);
                    accr = MFMA(hf0, W[6], accr);
                    accr = MFMA(hf1, W[7], accr);
                    accz = MFMA(hf0, W[8], accz);
                    accz = MFMA(hf1, W[9], accz);
                    f32x4 acchn = MFMA(hf0, W[10], bias3);
                    acchn = MFMA(hf1, W[11], acchn);
#pragma unroll
                    for (int i = 0; i < 4; ++i) {
                        const float rg = sigm(accr[i]);
                        const float zg = sigm(accz[i]);
                        const float ng = tanh_f(accxn[i] + rg * acchn[i]);
                        hreg[i] = ng + zg * (hreg[i] - ng);
                    }
#pragma unroll
                    for (int i = 0; i < 4; ++i) h1buf[pr][wrow + i * HS] = (_Float16)hreg[i];
                }
            }
            BAR();
        }
    }

    // final tick t=Tn: L1 computes h1(Tn-1)
    if (!isL0) {
        const int t = Tn;
        const int pr = (t & 1) ^ 1, pw = t & 1;
        const half8 xf0 = *(const half8*)&h0buf[pr][ardr];
        const half8 xf1 = *(const half8*)&h0buf[pr][ardr + 32];
        const half8 hf0 = *(const half8*)&h1buf[pw][ardr];
        const half8 hf1 = *(const half8*)&h1buf[pw][ardr + 32];
        f32x4 accr = MFMA(xf0, W[0], bias0);
        accr = MFMA(xf1, W[1], accr);
        f32x4 accz = MFMA(xf0, W[2], bias1);
        accz = MFMA(xf1, W[3], accz);
        f32x4 accxn = MFMA(xf0, W[4], bias2);
        accxn = MFMA(xf1, W[5], accxn);
        accr = MFMA(hf0, W[6], accr);
        accr = MFMA(hf1, W[7], accr);
        accz = MFMA(hf0, W[8], accz);
        accz = MFMA(hf1, W[9], accz);
        f32x4 acchn = MFMA(hf0, W[10], bias3);
        acchn = MFMA(hf1, W[11], acchn);
#pragma unroll
        for (int i = 0; i < 4; ++i) {
            const float rg = sigm(accr[i]);
            const float zg = sigm(accz[i]);
            const float ng = tanh_f(accxn[i] + rg * acchn[i]);
            hreg[i] = ng + zg * (hreg[i] - ng);
        }
        // epilogue staging: relu(h1_final)
#pragma unroll
        for (int i = 0; i < 4; ++i) fbuf[(q * 4 + i) * 64 + gc] = fmaxf(hreg[i], 0.0f);
    }
    __syncthreads();
    for (int idx = tid; idx < 16 * An; idx += 512) {
        const int row = idx / An, a = idx - row * An;
        float acc = fcb[a];
#pragma unroll 16
        for (int kk = 0; kk < Hn; ++kk) acc += fbuf[row * 64 + kk] * fcw[a * Hn + kk];
        out[(size_t)(r0 + row) * An + a] = acc;
    }
}

extern "C" void kernel_launch(void* const* d_in, const int* in_sizes, int n_in,
                              void* d_out, int out_size, void* d_ws, size_t ws_size,
                              hipStream_t stream) {
    const float* state = (const float*)d_in[0];
    const float* Wih0  = (const float*)d_in[1];
    const float* Whh0  = (const float*)d_in[2];
    const float* bih0  = (const float*)d_in[3];
    const float* bhh0  = (const float*)d_in[4];
    const float* Wih1  = (const float*)d_in[5];
    const float* Whh1  = (const float*)d_in[6];
    const float* bih1  = (const float*)d_in[7];
    const float* bhh1  = (const float*)d_in[8];
    const float* fcw   = (const float*)d_in[9];
    const float* fcb   = (const float*)d_in[10];
    float* out = (float*)d_out;

    const size_t nstate = (size_t)1024 * Tn * Fn;           // 67,108,864 elems
    if (ws_size >= nstate * sizeof(_Float16)) {
        _Float16* sf16 = (_Float16*)d_ws;
        state_to_f16<<<2048, 256, 0, stream>>>(state, sf16, (int)(nstate / 4));
        gru_fused2<true><<<64, 512, 0, stream>>>(state, sf16, Wih0, Whh0, bih0, bhh0,
                                                 Wih1, Whh1, bih1, bhh1, fcw, fcb, out);
    } else {
        gru_fused2<false><<<64, 512, 0, stream>>>(state, (const _Float16*)d_ws,
                                                  Wih0, Whh0, bih0, bhh0,
                                                  Wih1, Whh1, bih1, bhh1, fcw, fcb, out);
    }
}